// Round 1
// baseline (378.651 us; speedup 1.0000x reference)
//
#include <hip/hip_runtime.h>
#include <hip/hip_bf16.h>
#include <hip/hip_cooperative_groups.h>

namespace cg = cooperative_groups;

// Problem constants (fixed by reference). ALL float tensors are float32;
// indices int32. MFMA runs on bf16-converted fragments; accumulate + epilogue
// in fp32.
#define NB     131072   // batch
#define NCH    16       // charts
#define NPAIR  256      // (src,tgt) pair buckets
#define LDW    136      // LDS weight-row stride in bf16 elems (16B-aligned rows)
#define LDH    136      // LDS h-row stride in bf16 elems
#define LDO    132      // (fallback path only)
#define GRID_F 512      // fused kernel grid: 2 blocks/CU co-resident
#define RPB    (NB / GRID_F)   // rows per block in hist/scatter = 256

// Workspace layout (ints): hist @0 (256) | cursor/off @256 (257) | sorted @528 (NB)
#define WS_HIST   0
#define WS_OFF    256
#define WS_SORTED 528
#define WS_BYTES  ((WS_SORTED + NB) * 4)   // 526,400

typedef short short8 __attribute__((ext_vector_type(8)));   // 8 x bf16 (4 VGPRs) MFMA frag
typedef float f32x4  __attribute__((ext_vector_type(4)));   // MFMA accumulator / fp32 vec

__device__ __forceinline__ short bfbits(float x) {
    union { __hip_bfloat16 h; short s; } u;
    u.h = __float2bfloat16(x);
    return u.s;
}

// Load 8 consecutive fp32 (32B, 16B-aligned) and convert to a bf16x8 MFMA frag.
__device__ __forceinline__ short8 cvt_frag(const float* __restrict__ p) {
    const f32x4 lo = *(const f32x4*)p;
    const f32x4 hi = *(const f32x4*)(p + 4);
    short8 r;
    r[0] = bfbits(lo[0]); r[1] = bfbits(lo[1]); r[2] = bfbits(lo[2]); r[3] = bfbits(lo[3]);
    r[4] = bfbits(hi[0]); r[5] = bfbits(hi[1]); r[6] = bfbits(hi[2]); r[7] = bfbits(hi[3]);
    return r;
}

// =========================================================================
// FUSED cooperative kernel: hist -> sync -> scan -> sync -> scatter -> sync
// -> bucket GEMM. Grid 512 x 256 (2 blocks/CU: LDS ~73KB, regs capped by
// __launch_bounds__(256,2)). 2 blocks per bucket, alternating 128-row tiles.
// =========================================================================
__global__ __launch_bounds__(256, 2)
void k_fused(const float* __restrict__ z,
             const int* __restrict__ si,
             const int* __restrict__ ti,
             const float* __restrict__ encw,
             const float* __restrict__ decw,
             const float* __restrict__ cpar,
             const float* __restrict__ dpar,
             int* __restrict__ hist,
             int* __restrict__ cursor,
             int* __restrict__ sorted,
             float* __restrict__ out) {
    __shared__ int sh[NPAIR];          // per-block pair counts (phase1) -> reused read-only
    __shared__ int sAux[NPAIR];        // scan temp, then scatter base
    __shared__ int soff[NPAIR + 1];    // bucket offsets (kept in LDS for gemm phase)
    __shared__ int sRow[128];
    __shared__ __align__(16) __hip_bfloat16 sW2[128 * LDW];  // 34,816 B
    __shared__ __align__(16) __hip_bfloat16 sH[128 * LDH];   // 34,816 B (stages W1, then h)

    const int tid = threadIdx.x;
    const int bid = blockIdx.x;
    cg::grid_group grid = cg::this_grid();

    // ---------------- phase 1: histogram (exactly 1 row per thread) ----------
    sh[tid] = 0;
    __syncthreads();
    const int row = bid * RPB + tid;                            // coalesced
    const int key = (si[row] * NCH + ti[row]) & (NPAIR - 1);    // masked: never OOB
    const int rank = atomicAdd(&sh[key], 1);                    // rank kept for scatter
    __syncthreads();
    const int cnt = sh[tid];
    if (cnt) atomicAdd(&hist[tid], cnt);                        // device-scope
    grid.sync();

    // ---------------- phase 2: scan (redundant per block) + cursor init -----
    const int v = __hip_atomic_load(&hist[tid], __ATOMIC_RELAXED, __HIP_MEMORY_SCOPE_AGENT);
    sAux[tid] = v;
    __syncthreads();
#pragma unroll
    for (int d = 1; d < NPAIR; d <<= 1) {
        const int x = (tid >= d) ? sAux[tid - d] : 0;
        __syncthreads();
        sAux[tid] += x;
        __syncthreads();
    }
    soff[tid + 1] = sAux[tid];
    if (tid == 0) soff[0] = 0;
    if (bid == 0) cursor[tid] = sAux[tid] - v;                  // exclusive prefix
    grid.sync();

    // ---------------- phase 3: scatter ---------------------------------------
    sAux[tid] = cnt ? atomicAdd(&cursor[tid], cnt) : 0;         // block base per bin
    __syncthreads();
    const int slot = sAux[key] + rank;
    if ((unsigned)slot < (unsigned)NB) sorted[slot] = row;
    __threadfence();
    // read my bucket bounds from LDS before anything else
    const int bucket = bid >> 1;
    const int half   = bid & 1;
    const int beg = soff[bucket];
    const int end = soff[bucket + 1];
    grid.sync();

    // ---------------- phase 4: bucket GEMM -----------------------------------
    const int srcc = bucket >> 4;
    const int tgtc = bucket & (NCH - 1);
    const int lane = tid & 63;
    const int wv   = tid >> 6;
    const int lr   = lane & 15;                 // A: m-within-tile / B: n-within-tile
    const int lhi  = lane >> 4;                 // k-chunk selector (8 elems each)
    const int mb   = wv * 32;                   // this wave's row base in the tile

    // stage W1 (temp, into sH) and W2 (fp32 global, coalesced) -> bf16 LDS
    {
        const float* W1 = encw + srcc * 16384;  // [R=128][D=128] row-major fp32
        const float* W2 = decw + tgtc * 16384;  // [D=128][R=128] row-major fp32
#pragma unroll
        for (int it = 0; it < 8; ++it) {
            const int f = (it * 256 + tid) * 8;          // flat float index, 8 at a time
            const int r_ = f >> 7, c_ = f & 127;
            *(short8*)(sH  + r_ * LDH + c_) = cvt_frag(W1 + f);
            *(short8*)(sW2 + r_ * LDW + c_) = cvt_frag(W2 + f);
        }
    }
    __syncthreads();

    // hoist GEMM1 B-fragments into registers (loop-invariant across tiles);
    // sH is reused for h afterwards (compiler cannot remat these ds_reads
    // because sH is overwritten -> they stay in regs or spill, never stale).
    short8 b1[8][4];
#pragma unroll
    for (int nt = 0; nt < 8; ++nt)
#pragma unroll
        for (int k = 0; k < 4; ++k)
            b1[nt][k] = *(const short8*)(sH + (nt * 16 + lr) * LDH + k * 32 + lhi * 8);

    float cb[8], db[8];
#pragma unroll
    for (int nt = 0; nt < 8; ++nt) {
        cb[nt] = cpar[srcc * 128 + nt * 16 + lr];
        db[nt] = dpar[tgtc * 128 + nt * 16 + lr];
    }

    const int ntile = (end - beg + 127) >> 7;
    for (int tile = half; tile < ntile; tile += 2) {
        const int rbeg = beg + tile * 128;
        __syncthreads();   // protect sRow (prev epilogue) and sH (b1 hoist / prev GEMM2)
        if (tid < 128) {
            const int g = rbeg + tid;
            int vv = (g < end) ? sorted[g] : -1;
            sRow[tid] = ((unsigned)vv < (unsigned)NB) ? vv : -1;   // clamp: poison -> pad
        }
        __syncthreads();

        // -------- GEMM1: A rows gathered from global z (fp32 -> bf16) --------
        const int r0 = sRow[mb + lr];
        const int r1 = sRow[mb + 16 + lr];
        const float* pz0 = z + (long)(r0 < 0 ? 0 : r0) * 128 + lhi * 8;
        const float* pz1 = z + (long)(r1 < 0 ? 0 : r1) * 128 + lhi * 8;

        f32x4 acc[2][8];
#pragma unroll
        for (int mt = 0; mt < 2; ++mt)
#pragma unroll
            for (int nt = 0; nt < 8; ++nt) acc[mt][nt] = (f32x4)(0.0f);

#pragma unroll
        for (int k = 0; k < 4; ++k) {
            const short8 a0 = cvt_frag(pz0 + k * 32);
            const short8 a1 = cvt_frag(pz1 + k * 32);
#pragma unroll
            for (int nt = 0; nt < 8; ++nt) {
                acc[0][nt] = __builtin_amdgcn_mfma_f32_16x16x32_bf16(a0, b1[nt][k], acc[0][nt], 0, 0, 0);
                acc[1][nt] = __builtin_amdgcn_mfma_f32_16x16x32_bf16(a1, b1[nt][k], acc[1][nt], 0, 0, 0);
            }
        }

        // h (+ c bias) -> LDS bf16 [m][r]; C layout: row=(lane>>4)*4+reg, col=lane&15
#pragma unroll
        for (int nt = 0; nt < 8; ++nt)
#pragma unroll
            for (int mt = 0; mt < 2; ++mt) {
                const int rowb = mb + mt * 16 + lhi * 4;
                const int col = nt * 16 + lr;
#pragma unroll
                for (int r = 0; r < 4; ++r)
                    sH[(rowb + r) * LDH + col] = __float2bfloat16(acc[mt][nt][r] + cb[nt]);
            }
        __syncthreads();   // h crosses lanes via LDS — barrier required

        // -------- GEMM2: A = h from LDS (bf16), B = sW2 from LDS --------
#pragma unroll
        for (int mt = 0; mt < 2; ++mt)
#pragma unroll
            for (int nt = 0; nt < 8; ++nt) acc[mt][nt] = (f32x4)(0.0f);

#pragma unroll
        for (int k = 0; k < 4; ++k) {
            const short8 a0 = *(const short8*)(sH + (mb + lr) * LDH + k * 32 + lhi * 8);
            const short8 a1 = *(const short8*)(sH + (mb + 16 + lr) * LDH + k * 32 + lhi * 8);
#pragma unroll
            for (int nt = 0; nt < 8; ++nt) {
                const short8 b = *(const short8*)(sW2 + (nt * 16 + lr) * LDW + k * 32 + lhi * 8);
                acc[0][nt] = __builtin_amdgcn_mfma_f32_16x16x32_bf16(a0, b, acc[0][nt], 0, 0, 0);
                acc[1][nt] = __builtin_amdgcn_mfma_f32_16x16x32_bf16(a1, b, acc[1][nt], 0, 0, 0);
            }
        }

        // epilogue: direct stores from C-layout regs (+ d bias).
        // Per (mt,r): 16 lanes write 64B contiguous of one output row.
#pragma unroll
        for (int mt = 0; mt < 2; ++mt) {
            const int rb = mb + mt * 16 + lhi * 4;
            int gr[4];
#pragma unroll
            for (int r = 0; r < 4; ++r) gr[r] = sRow[rb + r];
#pragma unroll
            for (int nt = 0; nt < 8; ++nt)
#pragma unroll
                for (int r = 0; r < 4; ++r)
                    if (gr[r] >= 0)
                        out[(long)gr[r] * 128 + nt * 16 + lr] = acc[mt][nt][r] + db[nt];
        }
    }
}

// =========================================================================
// Fallback path: previous 5-kernel pipeline (unchanged), used if cooperative
// launch is unavailable or fails.
// =========================================================================
__global__ void k_init(int* __restrict__ hist) {
    hist[threadIdx.x] = 0;
}

__global__ __launch_bounds__(256) void k_hist(const int* __restrict__ si,
                                              const int* __restrict__ ti,
                                              int* __restrict__ hist) {
    __shared__ int sh[NPAIR];
    const int t = threadIdx.x;
    sh[t] = 0;
    __syncthreads();
    const int base = blockIdx.x * 2048 + t;
#pragma unroll
    for (int j = 0; j < 8; ++j) {
        const int i = base + j * 256;
        const int k = (si[i] * NCH + ti[i]) & (NPAIR - 1);
        atomicAdd(&sh[k], 1);
    }
    __syncthreads();
    if (sh[t]) atomicAdd(&hist[t], sh[t]);
}

__global__ __launch_bounds__(256) void k_scan(int* __restrict__ hist,
                                              int* __restrict__ off) {
    __shared__ int s[NPAIR];
    const int t = threadIdx.x;
    const int v = hist[t];
    s[t] = v;
    __syncthreads();
#pragma unroll
    for (int d = 1; d < NPAIR; d <<= 1) {
        const int x = (t >= d) ? s[t - d] : 0;
        __syncthreads();
        s[t] += x;
        __syncthreads();
    }
    off[t + 1] = s[t];
    if (t == 0) off[0] = 0;
    hist[t] = s[t] - v;
}

__global__ __launch_bounds__(256) void k_scatter(const int* __restrict__ si,
                                                 const int* __restrict__ ti,
                                                 int* __restrict__ cursor,
                                                 int* __restrict__ sorted) {
    __shared__ int sh[NPAIR];
    __shared__ int sbase[NPAIR];
    const int t = threadIdx.x;
    sh[t] = 0;
    __syncthreads();
    int key[8], rank[8];
    const int base = blockIdx.x * 2048 + t;
#pragma unroll
    for (int j = 0; j < 8; ++j) {
        const int i = base + j * 256;
        const int k = (si[i] * NCH + ti[i]) & (NPAIR - 1);
        key[j]  = k;
        rank[j] = atomicAdd(&sh[k], 1);
    }
    __syncthreads();
    sbase[t] = sh[t] ? atomicAdd(&cursor[t], sh[t]) : 0;
    __syncthreads();
#pragma unroll
    for (int j = 0; j < 8; ++j) {
        const int slot = sbase[key[j]] + rank[j];
        if (slot >= 0 && slot < NB)
            sorted[slot] = base + j * 256;
    }
}

__global__ __launch_bounds__(256, 1)
void k_gemm(const float* __restrict__ z,
            const float* __restrict__ encw,
            const float* __restrict__ decw,
            const float* __restrict__ cpar,
            const float* __restrict__ dpar,
            const int* __restrict__ off,
            const int* __restrict__ sorted,
            float* __restrict__ out) {
    __shared__ int sRow[128];
    __shared__ __align__(16) __hip_bfloat16 sW1[128 * LDW];
    __shared__ __align__(16) __hip_bfloat16 sW2[128 * LDW];
    __shared__ __align__(16) float sOut[128 * LDO];
    __hip_bfloat16* const sH = (__hip_bfloat16*)sOut;

    const int bucket = blockIdx.x;
    const int srcc = bucket >> 4;
    const int tgtc = bucket & (NCH - 1);
    const int beg = off[bucket];
    const int end = off[bucket + 1];

    const int tid  = threadIdx.x;
    const int lane = tid & 63;
    const int wv   = tid >> 6;
    const int lr   = lane & 15;
    const int lhi  = lane >> 4;
    const int mb   = wv * 32;

    {
        const float* W1 = encw + srcc * 16384;
        const float* W2 = decw + tgtc * 16384;
#pragma unroll
        for (int it = 0; it < 8; ++it) {
            const int f = (it * 256 + tid) * 8;
            const int row = f >> 7, col = f & 127;
            *(short8*)(sW1 + row * LDW + col) = cvt_frag(W1 + f);
            *(short8*)(sW2 + row * LDW + col) = cvt_frag(W2 + f);
        }
    }
    __syncthreads();

    short8 b1[8][4];
#pragma unroll
    for (int nt = 0; nt < 8; ++nt)
#pragma unroll
        for (int k = 0; k < 4; ++k)
            b1[nt][k] = *(const short8*)(sW1 + (nt * 16 + lr) * LDW + k * 32 + lhi * 8);

    float cb[8], db[8];
#pragma unroll
    for (int nt = 0; nt < 8; ++nt) {
        cb[nt] = cpar[srcc * 128 + nt * 16 + lr];
        db[nt] = dpar[tgtc * 128 + nt * 16 + lr];
    }

    const int ntile = (end - beg + 127) >> 7;
    for (int tile = 0; tile < ntile; ++tile) {
        const int rbeg = beg + tile * 128;
        __syncthreads();
        if (tid < 128) {
            const int g = rbeg + tid;
            int v = (g < end) ? sorted[g] : -1;
            sRow[tid] = ((unsigned)v < (unsigned)NB) ? v : -1;
        }
        __syncthreads();

        const int r0 = sRow[mb + lr];
        const int r1 = sRow[mb + 16 + lr];
        const float* pz0 = z + (long)(r0 < 0 ? 0 : r0) * 128 + lhi * 8;
        const float* pz1 = z + (long)(r1 < 0 ? 0 : r1) * 128 + lhi * 8;

        f32x4 acc[2][8];
#pragma unroll
        for (int mt = 0; mt < 2; ++mt)
#pragma unroll
            for (int nt = 0; nt < 8; ++nt) acc[mt][nt] = (f32x4)(0.0f);

#pragma unroll
        for (int k = 0; k < 4; ++k) {
            const short8 a0 = cvt_frag(pz0 + k * 32);
            const short8 a1 = cvt_frag(pz1 + k * 32);
#pragma unroll
            for (int nt = 0; nt < 8; ++nt) {
                acc[0][nt] = __builtin_amdgcn_mfma_f32_16x16x32_bf16(a0, b1[nt][k], acc[0][nt], 0, 0, 0);
                acc[1][nt] = __builtin_amdgcn_mfma_f32_16x16x32_bf16(a1, b1[nt][k], acc[1][nt], 0, 0, 0);
            }
        }

#pragma unroll
        for (int nt = 0; nt < 8; ++nt)
#pragma unroll
            for (int mt = 0; mt < 2; ++mt) {
                const int row = mb + mt * 16 + lhi * 4;
                const int col = nt * 16 + lr;
#pragma unroll
                for (int r = 0; r < 4; ++r)
                    sH[(row + r) * LDH + col] = __float2bfloat16(acc[mt][nt][r] + cb[nt]);
            }
        __syncthreads();

#pragma unroll
        for (int mt = 0; mt < 2; ++mt)
#pragma unroll
            for (int nt = 0; nt < 8; ++nt) acc[mt][nt] = (f32x4)(0.0f);

#pragma unroll
        for (int k = 0; k < 4; ++k) {
            const short8 a0 = *(const short8*)(sH + (mb + lr) * LDH + k * 32 + lhi * 8);
            const short8 a1 = *(const short8*)(sH + (mb + 16 + lr) * LDH + k * 32 + lhi * 8);
#pragma unroll
            for (int nt = 0; nt < 8; ++nt) {
                const short8 b = *(const short8*)(sW2 + (nt * 16 + lr) * LDW + k * 32 + lhi * 8);
                acc[0][nt] = __builtin_amdgcn_mfma_f32_16x16x32_bf16(a0, b, acc[0][nt], 0, 0, 0);
                acc[1][nt] = __builtin_amdgcn_mfma_f32_16x16x32_bf16(a1, b, acc[1][nt], 0, 0, 0);
            }
        }
        __syncthreads();

#pragma unroll
        for (int nt = 0; nt < 8; ++nt)
#pragma unroll
            for (int mt = 0; mt < 2; ++mt) {
                const int row = mb + mt * 16 + lhi * 4;
                const int col = nt * 16 + lr;
#pragma unroll
                for (int r = 0; r < 4; ++r)
                    sOut[(row + r) * LDO + col] = acc[mt][nt][r] + db[nt];
            }
        __syncthreads();

        {
            const int rr0 = tid >> 5;
            const int c4  = (tid & 31) * 4;
#pragma unroll
            for (int it = 0; it < 16; ++it) {
                const int rr = rr0 + it * 8;
                const int grow = sRow[rr];
                if (grow >= 0)
                    *(f32x4*)(out + (long)grow * 128 + c4) =
                        *(const f32x4*)(sOut + rr * LDO + c4);
            }
        }
    }
}

// Zero-workspace correct path: one wave per row, fp32 VALU dot products.
__global__ __launch_bounds__(256)
void k_fallback(const float* __restrict__ z,
                const int* __restrict__ si, const int* __restrict__ ti,
                const float* __restrict__ ew,
                const float* __restrict__ dw,
                const float* __restrict__ cp,
                const float* __restrict__ dp,
                float* __restrict__ out) {
    __shared__ float sh[4][128];
    const int lane = threadIdx.x & 63, wv = threadIdx.x >> 6;
    for (int row = blockIdx.x * 4 + wv; row < NB; row += (int)gridDim.x * 4) {
        const int sc = si[row] & (NCH - 1), tc = ti[row] & (NCH - 1);
        const float* zr = z + (long)row * 128;
        const float* W1 = ew + sc * 16384;
        float h0 = cp[sc * 128 + lane];
        float h1 = cp[sc * 128 + lane + 64];
        for (int d = 0; d < 128; ++d) {
            const float zv = zr[d];
            h0 += zv * W1[lane * 128 + d];
            h1 += zv * W1[(lane + 64) * 128 + d];
        }
        sh[wv][lane] = h0;
        sh[wv][lane + 64] = h1;
        __syncthreads();
        const float* W2 = dw + tc * 16384;
        float o0 = dp[tc * 128 + lane];
        float o1 = dp[tc * 128 + lane + 64];
        for (int r = 0; r < 128; ++r) {
            const float hv = sh[wv][r];
            o0 += hv * W2[lane * 128 + r];
            o1 += hv * W2[(lane + 64) * 128 + r];
        }
        out[(long)row * 128 + lane] = o0;
        out[(long)row * 128 + lane + 64] = o1;
        __syncthreads();
    }
}

// ----------------------------------------------------------------- launch ---
extern "C" void kernel_launch(void* const* d_in, const int* in_sizes, int n_in,
                              void* d_out, int out_size, void* d_ws, size_t ws_size,
                              hipStream_t stream) {
    const float* z  = (const float*)d_in[0];
    const int*   si = (const int*)d_in[1];
    const int*   ti = (const int*)d_in[2];
    const float* ew = (const float*)d_in[3];
    const float* dw = (const float*)d_in[4];
    const float* cp = (const float*)d_in[5];
    const float* dp = (const float*)d_in[6];
    float* out = (float*)d_out;

    if (ws_size >= (size_t)WS_BYTES) {
        int* hist   = (int*)d_ws + WS_HIST;    // 256 (fused: hist; old path: hist->cursor)
        int* curoff = (int*)d_ws + WS_OFF;     // 257 (fused: cursor; old path: off)
        int* sorted = (int*)d_ws + WS_SORTED;  // NB

        static int coopChecked = 0, coopOK = 0;
        if (!coopChecked) {
            coopChecked = 1;
            int dev = 0;
            (void)hipGetDevice(&dev);
            (void)hipDeviceGetAttribute(&coopOK, hipDeviceAttributeCooperativeLaunch, dev);
        }

        if (coopOK) {
            (void)hipMemsetAsync(hist, 0, NPAIR * sizeof(int), stream);
            void* args[] = {
                (void*)&z, (void*)&si, (void*)&ti, (void*)&ew, (void*)&dw,
                (void*)&cp, (void*)&dp, (void*)&hist, (void*)&curoff,
                (void*)&sorted, (void*)&out
            };
            hipError_t e = hipLaunchCooperativeKernel((const void*)k_fused,
                                                      dim3(GRID_F), dim3(256),
                                                      args, 0, stream);
            if (e == hipSuccess) return;
            (void)hipGetLastError();   // clear and fall through to legacy path
        }

        k_init<<<1, NPAIR, 0, stream>>>(hist);
        k_hist<<<64, 256, 0, stream>>>(si, ti, hist);
        k_scan<<<1, NPAIR, 0, stream>>>(hist, curoff);
        k_scatter<<<64, 256, 0, stream>>>(si, ti, hist, sorted);
        k_gemm<<<NPAIR, 256, 0, stream>>>(z, ew, dw, cp, dp, curoff, sorted, out);
    } else {
        k_fallback<<<1024, 256, 0, stream>>>(z, si, ti, ew, dw, cp, dp, out);
    }
}

// Round 2
// 155.661 us; speedup vs baseline: 2.4325x; 2.4325x over previous
//
#include <hip/hip_runtime.h>
#include <hip/hip_bf16.h>

// Problem constants (fixed by reference). ALL float tensors are float32;
// indices int32. MFMA runs on bf16-converted fragments; accumulate + epilogue
// in fp32; output staged in LDS and stored fp32 fully coalesced.
#define NB     131072   // batch
#define NCH    16       // charts
#define NPAIR  256      // (src,tgt) pair buckets
#define LDW    136      // LDS weight-row stride in bf16 elems (16B-aligned rows)
#define LDH    136      // LDS h-row stride in bf16 elems
#define LDO    132      // LDS out-row stride in fp32 elems

// Workspace layout (ints): hist/cursor @0 (256) | off @256 (257) | sorted @528 (NB)
#define WS_HIST   0
#define WS_OFF    256
#define WS_SORTED 528
#define WS_BYTES  ((WS_SORTED + NB) * 4)   // 526,400

typedef short short8 __attribute__((ext_vector_type(8)));   // 8 x bf16 (4 VGPRs) MFMA frag
typedef float f32x4  __attribute__((ext_vector_type(4)));   // MFMA accumulator / fp32 vec

__device__ __forceinline__ short bfbits(float x) {
    union { __hip_bfloat16 h; short s; } u;
    u.h = __float2bfloat16(x);
    return u.s;
}

// Load 8 consecutive fp32 (32B, 16B-aligned) and convert to a bf16x8 MFMA frag.
__device__ __forceinline__ short8 cvt_frag(const float* __restrict__ p) {
    const f32x4 lo = *(const f32x4*)p;
    const f32x4 hi = *(const f32x4*)(p + 4);
    short8 r;
    r[0] = bfbits(lo[0]); r[1] = bfbits(lo[1]); r[2] = bfbits(lo[2]); r[3] = bfbits(lo[3]);
    r[4] = bfbits(hi[0]); r[5] = bfbits(hi[1]); r[6] = bfbits(hi[2]); r[7] = bfbits(hi[3]);
    return r;
}

// ---------------------------------------------------------------- k_init ----
__global__ void k_init(int* __restrict__ hist) {
    hist[threadIdx.x] = 0;
}

// ---------------------------------------------------------------- k_hist ----
__global__ __launch_bounds__(256) void k_hist(const int* __restrict__ si,
                                              const int* __restrict__ ti,
                                              int* __restrict__ hist) {
    __shared__ int sh[NPAIR];
    const int t = threadIdx.x;
    sh[t] = 0;
    __syncthreads();
    const int base = blockIdx.x * 1024 + t;
#pragma unroll
    for (int j = 0; j < 4; ++j) {
        const int i = base + j * 256;                       // coalesced
        const int k = (si[i] * NCH + ti[i]) & (NPAIR - 1);  // masked: never OOB
        atomicAdd(&sh[k], 1);
    }
    __syncthreads();
    if (sh[t]) atomicAdd(&hist[t], sh[t]);
}

// ---------------------------------------------------------------- k_scan ----
__global__ __launch_bounds__(256) void k_scan(int* __restrict__ hist,
                                              int* __restrict__ off) {
    __shared__ int s[NPAIR];
    const int t = threadIdx.x;
    const int v = hist[t];
    s[t] = v;
    __syncthreads();
#pragma unroll
    for (int d = 1; d < NPAIR; d <<= 1) {
        const int x = (t >= d) ? s[t - d] : 0;
        __syncthreads();
        s[t] += x;
        __syncthreads();
    }
    off[t + 1] = s[t];                 // inclusive -> off[1..256]
    if (t == 0) off[0] = 0;
    hist[t] = s[t] - v;                // exclusive prefix -> cursor start
}

// ------------------------------------------------------------- k_scatter ----
__global__ __launch_bounds__(256) void k_scatter(const int* __restrict__ si,
                                                 const int* __restrict__ ti,
                                                 int* __restrict__ cursor,
                                                 int* __restrict__ sorted) {
    __shared__ int sh[NPAIR];
    __shared__ int sbase[NPAIR];
    const int t = threadIdx.x;
    sh[t] = 0;
    __syncthreads();
    int key[4], rank[4];
    const int base = blockIdx.x * 1024 + t;
#pragma unroll
    for (int j = 0; j < 4; ++j) {
        const int i = base + j * 256;
        const int k = (si[i] * NCH + ti[i]) & (NPAIR - 1);
        key[j]  = k;
        rank[j] = atomicAdd(&sh[k], 1);
    }
    __syncthreads();
    sbase[t] = sh[t] ? atomicAdd(&cursor[t], sh[t]) : 0;
    __syncthreads();
#pragma unroll
    for (int j = 0; j < 4; ++j) {
        const int slot = sbase[key[j]] + rank[j];
        if (slot >= 0 && slot < NB)
            sorted[slot] = base + j * 256;
    }
}

// ---------------------------------------------------------------- k_gemm ----
// ONE BLOCK PER BUCKET (grid 256 = 1 block/CU), now 512 threads = 8 waves
// -> 2 waves/SIMD (round-0 version had 4 waves = 1 wave/SIMD, fully
// latency-exposed: all pipes <8%). Each wave owns 16 rows of the 128-row
// tile (acc[8] = 32 regs). NO register hoist of GEMM1 B-fragments: the
// round-1 fused kernel proved a 128-VGPR hoist under a 256-reg budget
// spills into the inner loop (5x regression). B comes from resident sW1
// per k-step, same pattern as GEMM2 -- ds_read hides under 2-wave overlap.
__global__ __launch_bounds__(512, 2)
void k_gemm(const float* __restrict__ z,
            const float* __restrict__ encw,
            const float* __restrict__ decw,
            const float* __restrict__ cpar,
            const float* __restrict__ dpar,
            const int* __restrict__ off,
            const int* __restrict__ sorted,
            float* __restrict__ out) {
    __shared__ int sRow[128];
    __shared__ __align__(16) __hip_bfloat16 sW1[128 * LDW];  // 34,816 B
    __shared__ __align__(16) __hip_bfloat16 sW2[128 * LDW];  // 34,816 B
    __shared__ __align__(16) float sOut[128 * LDO];          // 67,584 B
    __hip_bfloat16* const sH = (__hip_bfloat16*)sOut;        // overlay: h tile (35 KB)

    const int bucket = blockIdx.x;
    const int srcc = bucket >> 4;
    const int tgtc = bucket & (NCH - 1);
    const int beg = off[bucket];
    const int end = off[bucket + 1];

    const int tid  = threadIdx.x;
    const int lane = tid & 63;
    const int wv   = tid >> 6;                  // 0..7
    const int lr   = lane & 15;                 // A: m-within-tile / B: n-within-tile
    const int lhi  = lane >> 4;                 // k-chunk selector (8 elems each)
    const int mb   = wv * 16;                   // this wave's row base in the tile

    // ---- stage W1/W2 (fp32 global, coalesced) -> bf16 LDS, once per block ----
    {
        const float* W1 = encw + srcc * 16384;  // [R=128][D=128] row-major fp32
        const float* W2 = decw + tgtc * 16384;  // [D=128][R=128] row-major fp32
#pragma unroll
        for (int it = 0; it < 4; ++it) {
            const int f = (it * 512 + tid) * 8;          // flat float index, 8 at a time
            const int row = f >> 7, col = f & 127;
            *(short8*)(sW1 + row * LDW + col) = cvt_frag(W1 + f);
            *(short8*)(sW2 + row * LDW + col) = cvt_frag(W2 + f);
        }
    }
    __syncthreads();

    float cb[8], db[8];
#pragma unroll
    for (int nt = 0; nt < 8; ++nt) {
        cb[nt] = cpar[srcc * 128 + nt * 16 + lr];
        db[nt] = dpar[tgtc * 128 + nt * 16 + lr];
    }

    const int ntile = (end - beg + 127) >> 7;
    for (int tile = 0; tile < ntile; ++tile) {
        const int rbeg = beg + tile * 128;
        __syncthreads();   // protect sRow/sOut from previous iteration's readers
        if (tid < 128) {
            const int g = rbeg + tid;
            int v = (g < end) ? sorted[g] : -1;
            sRow[tid] = ((unsigned)v < (unsigned)NB) ? v : -1;   // clamp: poison -> pad
        }
        __syncthreads();

        // -------- GEMM1: A rows gathered from global z (fp32 -> bf16) --------
        const int r0 = sRow[mb + lr];
        const float* pz0 = z + (long)(r0 < 0 ? 0 : r0) * 128 + lhi * 8;

        f32x4 acc[8];
#pragma unroll
        for (int nt = 0; nt < 8; ++nt) acc[nt] = (f32x4)(0.0f);

#pragma unroll
        for (int k = 0; k < 4; ++k) {
            const short8 a0 = cvt_frag(pz0 + k * 32);
#pragma unroll
            for (int nt = 0; nt < 8; ++nt) {
                const short8 b = *(const short8*)(sW1 + (nt * 16 + lr) * LDW + k * 32 + lhi * 8);
                acc[nt] = __builtin_amdgcn_mfma_f32_16x16x32_bf16(a0, b, acc[nt], 0, 0, 0);
            }
        }

        // h (+ c bias) -> LDS bf16 [m][r]; C layout: row=(lane>>4)*4+reg, col=lane&15
#pragma unroll
        for (int nt = 0; nt < 8; ++nt) {
            const int row = mb + lhi * 4;
            const int col = nt * 16 + lr;
#pragma unroll
            for (int r = 0; r < 4; ++r)
                sH[(row + r) * LDH + col] = __float2bfloat16(acc[nt][r] + cb[nt]);
        }
        __syncthreads();   // h crosses lanes via LDS — barrier required

        // -------- GEMM2: A = h from LDS (bf16), B = sW2 from LDS --------
#pragma unroll
        for (int nt = 0; nt < 8; ++nt) acc[nt] = (f32x4)(0.0f);

#pragma unroll
        for (int k = 0; k < 4; ++k) {
            const short8 a0 = *(const short8*)(sH + (mb + lr) * LDH + k * 32 + lhi * 8);
#pragma unroll
            for (int nt = 0; nt < 8; ++nt) {
                const short8 b = *(const short8*)(sW2 + (nt * 16 + lr) * LDW + k * 32 + lhi * 8);
                acc[nt] = __builtin_amdgcn_mfma_f32_16x16x32_bf16(a0, b, acc[nt], 0, 0, 0);
            }
        }
        __syncthreads();   // all sH reads done before overwriting the overlay

        // epilogue (+ d bias) -> sOut fp32 [m][e]
#pragma unroll
        for (int nt = 0; nt < 8; ++nt) {
            const int row = mb + lhi * 4;
            const int col = nt * 16 + lr;
#pragma unroll
            for (int r = 0; r < 4; ++r)
                sOut[(row + r) * LDO + col] = acc[nt][r] + db[nt];
        }
        __syncthreads();

        // coalesced store: 32 lanes x 16B = one whole 512B row
        {
            const int rr0 = tid >> 5;          // 0..15
            const int c4  = (tid & 31) * 4;    // float offset, 16B granules
#pragma unroll
            for (int it = 0; it < 8; ++it) {
                const int rr = rr0 + it * 16;
                const int grow = sRow[rr];
                if (grow >= 0)
                    *(f32x4*)(out + (long)grow * 128 + c4) =
                        *(const f32x4*)(sOut + rr * LDO + c4);
            }
        }
    }
}

// ------------------------------------------------------------- k_fallback ---
// Zero-workspace correct path: one wave per row, fp32 VALU dot products.
__global__ __launch_bounds__(256)
void k_fallback(const float* __restrict__ z,
                const int* __restrict__ si, const int* __restrict__ ti,
                const float* __restrict__ ew,
                const float* __restrict__ dw,
                const float* __restrict__ cp,
                const float* __restrict__ dp,
                float* __restrict__ out) {
    __shared__ float sh[4][128];
    const int lane = threadIdx.x & 63, wv = threadIdx.x >> 6;
    for (int row = blockIdx.x * 4 + wv; row < NB; row += (int)gridDim.x * 4) {
        const int sc = si[row] & (NCH - 1), tc = ti[row] & (NCH - 1);
        const float* zr = z + (long)row * 128;
        const float* W1 = ew + sc * 16384;
        float h0 = cp[sc * 128 + lane];
        float h1 = cp[sc * 128 + lane + 64];
        for (int d = 0; d < 128; ++d) {
            const float zv = zr[d];
            h0 += zv * W1[lane * 128 + d];
            h1 += zv * W1[(lane + 64) * 128 + d];
        }
        sh[wv][lane] = h0;
        sh[wv][lane + 64] = h1;
        __syncthreads();
        const float* W2 = dw + tc * 16384;
        float o0 = dp[tc * 128 + lane];
        float o1 = dp[tc * 128 + lane + 64];
        for (int r = 0; r < 128; ++r) {
            const float hv = sh[wv][r];
            o0 += hv * W2[lane * 128 + r];
            o1 += hv * W2[(lane + 64) * 128 + r];
        }
        out[(long)row * 128 + lane] = o0;
        out[(long)row * 128 + lane + 64] = o1;
        __syncthreads();
    }
}

// ----------------------------------------------------------------- launch ---
extern "C" void kernel_launch(void* const* d_in, const int* in_sizes, int n_in,
                              void* d_out, int out_size, void* d_ws, size_t ws_size,
                              hipStream_t stream) {
    // Reference dtypes: all float tensors float32, indices int32, output float32.
    const float* z  = (const float*)d_in[0];
    const int*   si = (const int*)d_in[1];
    const int*   ti = (const int*)d_in[2];
    const float* ew = (const float*)d_in[3];
    const float* dw = (const float*)d_in[4];
    const float* cp = (const float*)d_in[5];
    const float* dp = (const float*)d_in[6];
    float* out = (float*)d_out;

    if (ws_size >= (size_t)WS_BYTES) {
        int* hist   = (int*)d_ws + WS_HIST;    // 256, becomes cursor after scan
        int* off    = (int*)d_ws + WS_OFF;     // 257
        int* sorted = (int*)d_ws + WS_SORTED;  // NB

        k_init<<<1, NPAIR, 0, stream>>>(hist);
        k_hist<<<128, 256, 0, stream>>>(si, ti, hist);
        k_scan<<<1, NPAIR, 0, stream>>>(hist, off);
        k_scatter<<<128, 256, 0, stream>>>(si, ti, hist, sorted);
        k_gemm<<<NPAIR, 512, 0, stream>>>(z, ew, dw, cp, dp, off, sorted, out);
    } else {
        k_fallback<<<1024, 256, 0, stream>>>(z, si, ti, ew, dw, cp, dp, out);
    }
}

// Round 3
// 146.921 us; speedup vs baseline: 2.5772x; 1.0595x over previous
//
#include <hip/hip_runtime.h>
#include <hip/hip_bf16.h>

// Problem constants (fixed by reference). ALL float tensors are float32;
// indices int32. MFMA runs on bf16-converted fragments; accumulate + epilogue
// in fp32.
#define NB     131072   // batch
#define NCH    16       // charts
#define NPAIR  256      // (src,tgt) pair buckets
#define LDW    136      // LDS weight-row stride in bf16 elems (16B-aligned rows)
#define LDH    136      // LDS h-row stride in bf16 elems
#define LDO    132      // (fallback path only)
#define CAP    1024     // sorted-slice chunk capacity (bucket avg 512, max ~640)

// Workspace layout (ints): hist/cursor @0 (256) | off @256 (257) | sorted @528 (NB)
#define WS_HIST   0
#define WS_OFF    256
#define WS_SORTED 528
#define WS_BYTES  ((WS_SORTED + NB) * 4)   // 526,400

typedef short short8 __attribute__((ext_vector_type(8)));   // 8 x bf16 (4 VGPRs) MFMA frag
typedef float f32x4  __attribute__((ext_vector_type(4)));   // MFMA accumulator / fp32 vec

__device__ __forceinline__ short bfbits(float x) {
    union { __hip_bfloat16 h; short s; } u;
    u.h = __float2bfloat16(x);
    return u.s;
}

// Load 8 consecutive fp32 (32B, 16B-aligned) and convert to a bf16x8 MFMA frag.
__device__ __forceinline__ short8 cvt_frag(const float* __restrict__ p) {
    const f32x4 lo = *(const f32x4*)p;
    const f32x4 hi = *(const f32x4*)(p + 4);
    short8 r;
    r[0] = bfbits(lo[0]); r[1] = bfbits(lo[1]); r[2] = bfbits(lo[2]); r[3] = bfbits(lo[3]);
    r[4] = bfbits(hi[0]); r[5] = bfbits(hi[1]); r[6] = bfbits(hi[2]); r[7] = bfbits(hi[3]);
    return r;
}

// ---------------------------------------------------------------- k_init ----
__global__ void k_init(int* __restrict__ hist) {
    hist[threadIdx.x] = 0;
}

// ---------------------------------------------------------------- k_hist ----
__global__ __launch_bounds__(256) void k_hist(const int* __restrict__ si,
                                              const int* __restrict__ ti,
                                              int* __restrict__ hist) {
    __shared__ int sh[NPAIR];
    const int t = threadIdx.x;
    sh[t] = 0;
    __syncthreads();
    const int base = blockIdx.x * 1024 + t;
#pragma unroll
    for (int j = 0; j < 4; ++j) {
        const int i = base + j * 256;                       // coalesced
        const int k = (si[i] * NCH + ti[i]) & (NPAIR - 1);  // masked: never OOB
        atomicAdd(&sh[k], 1);
    }
    __syncthreads();
    if (sh[t]) atomicAdd(&hist[t], sh[t]);
}

// ---------------------------------------------------------------- k_scan ----
__global__ __launch_bounds__(256) void k_scan(int* __restrict__ hist,
                                              int* __restrict__ off) {
    __shared__ int s[NPAIR];
    const int t = threadIdx.x;
    const int v = hist[t];
    s[t] = v;
    __syncthreads();
#pragma unroll
    for (int d = 1; d < NPAIR; d <<= 1) {
        const int x = (t >= d) ? s[t - d] : 0;
        __syncthreads();
        s[t] += x;
        __syncthreads();
    }
    off[t + 1] = s[t];                 // inclusive -> off[1..256]
    if (t == 0) off[0] = 0;
    hist[t] = s[t] - v;                // exclusive prefix -> cursor start
}

// ------------------------------------------------------------- k_scatter ----
__global__ __launch_bounds__(256) void k_scatter(const int* __restrict__ si,
                                                 const int* __restrict__ ti,
                                                 int* __restrict__ cursor,
                                                 int* __restrict__ sorted) {
    __shared__ int sh[NPAIR];
    __shared__ int sbase[NPAIR];
    const int t = threadIdx.x;
    sh[t] = 0;
    __syncthreads();
    int key[4], rank[4];
    const int base = blockIdx.x * 1024 + t;
#pragma unroll
    for (int j = 0; j < 4; ++j) {
        const int i = base + j * 256;
        const int k = (si[i] * NCH + ti[i]) & (NPAIR - 1);
        key[j]  = k;
        rank[j] = atomicAdd(&sh[k], 1);
    }
    __syncthreads();
    sbase[t] = sh[t] ? atomicAdd(&cursor[t], sh[t]) : 0;
    __syncthreads();
#pragma unroll
    for (int j = 0; j < 4; ++j) {
        const int slot = sbase[key[j]] + rank[j];
        if (slot >= 0 && slot < NB)
            sorted[slot] = base + j * 256;
    }
}

// ---------------------------------------------------------------- k_gemm ----
// ONE BLOCK PER BUCKET, 512 threads = 8 waves, WAVE-AUTONOMOUS main loop.
// Round-2 showed the barrier-locked design leaves all pipes <10%: both
// waves/SIMD stall together at every gather + at the vmcnt(0) write-drain
// the compiler emits before each s_barrier. Here each wave independently
// processes 16-row groups with ZERO main-loop barriers:
//   - z gathered straight into registers (double-buffered prefetch: the
//     next group's 8 dwordx4 loads are issued before the current group's
//     MFMA work, hiding ~700-900cy HBM latency under compute),
//   - h lives in a PER-WAVE LDS slice (cross-lane exchange within one
//     wave: DS ops are in-order per wave, no barrier needed),
//   - output stored directly from C-layout regs (64B segments; L2 merges).
// Prologue (weights + sorted-slice -> LDS) keeps the only barriers.
__global__ __launch_bounds__(512, 2)
void k_gemm(const float* __restrict__ z,
            const float* __restrict__ encw,
            const float* __restrict__ decw,
            const float* __restrict__ cpar,
            const float* __restrict__ dpar,
            const int* __restrict__ off,
            const int* __restrict__ sorted,
            float* __restrict__ out) {
    __shared__ int sRowLds[CAP];                             //  4,096 B
    __shared__ __align__(16) __hip_bfloat16 sW1[128 * LDW];  // 34,816 B
    __shared__ __align__(16) __hip_bfloat16 sW2[128 * LDW];  // 34,816 B
    __shared__ __align__(16) __hip_bfloat16 sH[8 * 16 * LDH];// 34,816 B (per-wave 16-row slices)

    const int bucket = blockIdx.x;
    const int srcc = bucket >> 4;
    const int tgtc = bucket & (NCH - 1);
    const int beg = off[bucket];
    const int end = off[bucket + 1];

    const int tid  = threadIdx.x;
    const int lane = tid & 63;
    const int wv   = tid >> 6;                  // 0..7
    const int lr   = lane & 15;                 // A: m-within-group / B: n-within-tile
    const int lhi  = lane >> 4;                 // k-chunk selector (8 elems each)

    // ---- stage W1/W2 (fp32 global, coalesced) -> bf16 LDS, once per block ----
    {
        const float* W1 = encw + srcc * 16384;  // [R=128][D=128] row-major fp32
        const float* W2 = decw + tgtc * 16384;  // [D=128][R=128] row-major fp32
#pragma unroll
        for (int it = 0; it < 4; ++it) {
            const int f = (it * 512 + tid) * 8;          // flat float index, 8 at a time
            const int row = f >> 7, col = f & 127;
            *(short8*)(sW1 + row * LDW + col) = cvt_frag(W1 + f);
            *(short8*)(sW2 + row * LDW + col) = cvt_frag(W2 + f);
        }
    }

    float cb[8], db[8];
#pragma unroll
    for (int nt = 0; nt < 8; ++nt) {
        cb[nt] = cpar[srcc * 128 + nt * 16 + lr];
        db[nt] = dpar[tgtc * 128 + nt * 16 + lr];
    }

    __hip_bfloat16* const hs = sH + wv * (16 * LDH);   // this wave's h slice

    // prefetch: issue the 8 z-loads (one 16-row group's A-operand slice) early
    auto pf = [&](int g, f32x4* buf) {
        const int rr = sRowLds[(g << 4) + lr];
        const float* p = z + (long)(rr < 0 ? 0 : rr) * 128 + lhi * 8;
#pragma unroll
        for (int k = 0; k < 4; ++k) {
            buf[2 * k]     = *(const f32x4*)(p + k * 32);
            buf[2 * k + 1] = *(const f32x4*)(p + k * 32 + 4);
        }
    };

    // full pipeline for one 16-row group: GEMM1 (regs x sW1) -> h in per-wave
    // LDS slice -> GEMM2 (hs x sW2) -> direct global stores.
    auto do_group = [&](int g, const f32x4* buf) {
        f32x4 acc[8];
#pragma unroll
        for (int nt = 0; nt < 8; ++nt) acc[nt] = (f32x4)(0.0f);

#pragma unroll
        for (int k = 0; k < 4; ++k) {
            const f32x4 lo = buf[2 * k], hi = buf[2 * k + 1];
            short8 a;
            a[0] = bfbits(lo[0]); a[1] = bfbits(lo[1]); a[2] = bfbits(lo[2]); a[3] = bfbits(lo[3]);
            a[4] = bfbits(hi[0]); a[5] = bfbits(hi[1]); a[6] = bfbits(hi[2]); a[7] = bfbits(hi[3]);
#pragma unroll
            for (int nt = 0; nt < 8; ++nt) {
                const short8 b = *(const short8*)(sW1 + (nt * 16 + lr) * LDW + k * 32 + lhi * 8);
                acc[nt] = __builtin_amdgcn_mfma_f32_16x16x32_bf16(a, b, acc[nt], 0, 0, 0);
            }
        }

        // h (+ c bias) -> per-wave LDS slice; C layout: row=lhi*4+r, col=nt*16+lr
#pragma unroll
        for (int nt = 0; nt < 8; ++nt)
#pragma unroll
            for (int r = 0; r < 4; ++r)
                hs[(lhi * 4 + r) * LDH + nt * 16 + lr] = __float2bfloat16(acc[nt][r] + cb[nt]);
        // same-wave DS in-order + compiler-preserved aliasing order: no barrier.

#pragma unroll
        for (int nt = 0; nt < 8; ++nt) acc[nt] = (f32x4)(0.0f);

#pragma unroll
        for (int k = 0; k < 4; ++k) {
            const short8 a = *(const short8*)(hs + lr * LDH + k * 32 + lhi * 8);
#pragma unroll
            for (int nt = 0; nt < 8; ++nt) {
                const short8 b = *(const short8*)(sW2 + (nt * 16 + lr) * LDW + k * 32 + lhi * 8);
                acc[nt] = __builtin_amdgcn_mfma_f32_16x16x32_bf16(a, b, acc[nt], 0, 0, 0);
            }
        }

        // direct stores (+ d bias): per (nt,r) 16 lanes write 64B contiguous
        int grow[4];
#pragma unroll
        for (int r = 0; r < 4; ++r) grow[r] = sRowLds[(g << 4) + lhi * 4 + r];
#pragma unroll
        for (int nt = 0; nt < 8; ++nt)
#pragma unroll
            for (int r = 0; r < 4; ++r)
                if (grow[r] >= 0)
                    out[(long)grow[r] * 128 + nt * 16 + lr] = acc[nt][r] + db[nt];
    };

    // chunked over the bucket (one chunk in practice: buckets avg 512, CAP 1024)
    for (int cb0 = beg; cb0 < end; cb0 += CAP) {
        const int cnt = min(end - cb0, CAP);
        __syncthreads();                       // protect sRowLds reuse across chunks
        for (int i = tid; i < CAP; i += 512) {
            int v = (i < cnt) ? sorted[cb0 + i] : -1;
            sRowLds[i] = ((unsigned)v < (unsigned)NB) ? v : -1;   // clamp: poison -> pad
        }
        __syncthreads();                       // weights (first chunk) + rows visible

        const int ng = (cnt + 15) >> 4;        // 16-row groups in this chunk
        int g = wv;
        f32x4 pfA[8], pfB[8];
        if (g < ng) pf(g, pfA);
        while (g < ng) {
            int g1 = g + 8;
            if (g1 < ng) pf(g1, pfB);          // issue next loads before compute
            do_group(g, pfA);
            g = g1;
            if (g >= ng) break;
            int g2 = g + 8;
            if (g2 < ng) pf(g2, pfA);
            do_group(g, pfB);
            g = g2;
        }
    }
}

// ------------------------------------------------------------- k_fallback ---
// Zero-workspace correct path: one wave per row, fp32 VALU dot products.
__global__ __launch_bounds__(256)
void k_fallback(const float* __restrict__ z,
                const int* __restrict__ si, const int* __restrict__ ti,
                const float* __restrict__ ew,
                const float* __restrict__ dw,
                const float* __restrict__ cp,
                const float* __restrict__ dp,
                float* __restrict__ out) {
    __shared__ float sh[4][128];
    const int lane = threadIdx.x & 63, wv = threadIdx.x >> 6;
    for (int row = blockIdx.x * 4 + wv; row < NB; row += (int)gridDim.x * 4) {
        const int sc = si[row] & (NCH - 1), tc = ti[row] & (NCH - 1);
        const float* zr = z + (long)row * 128;
        const float* W1 = ew + sc * 16384;
        float h0 = cp[sc * 128 + lane];
        float h1 = cp[sc * 128 + lane + 64];
        for (int d = 0; d < 128; ++d) {
            const float zv = zr[d];
            h0 += zv * W1[lane * 128 + d];
            h1 += zv * W1[(lane + 64) * 128 + d];
        }
        sh[wv][lane] = h0;
        sh[wv][lane + 64] = h1;
        __syncthreads();
        const float* W2 = dw + tc * 16384;
        float o0 = dp[tc * 128 + lane];
        float o1 = dp[tc * 128 + lane + 64];
        for (int r = 0; r < 128; ++r) {
            const float hv = sh[wv][r];
            o0 += hv * W2[lane * 128 + r];
            o1 += hv * W2[(lane + 64) * 128 + r];
        }
        out[(long)row * 128 + lane] = o0;
        out[(long)row * 128 + lane + 64] = o1;
        __syncthreads();
    }
}

// ----------------------------------------------------------------- launch ---
extern "C" void kernel_launch(void* const* d_in, const int* in_sizes, int n_in,
                              void* d_out, int out_size, void* d_ws, size_t ws_size,
                              hipStream_t stream) {
    // Reference dtypes: all float tensors float32, indices int32, output float32.
    const float* z  = (const float*)d_in[0];
    const int*   si = (const int*)d_in[1];
    const int*   ti = (const int*)d_in[2];
    const float* ew = (const float*)d_in[3];
    const float* dw = (const float*)d_in[4];
    const float* cp = (const float*)d_in[5];
    const float* dp = (const float*)d_in[6];
    float* out = (float*)d_out;

    if (ws_size >= (size_t)WS_BYTES) {
        int* hist   = (int*)d_ws + WS_HIST;    // 256, becomes cursor after scan
        int* off    = (int*)d_ws + WS_OFF;     // 257
        int* sorted = (int*)d_ws + WS_SORTED;  // NB

        k_init<<<1, NPAIR, 0, stream>>>(hist);
        k_hist<<<128, 256, 0, stream>>>(si, ti, hist);
        k_scan<<<1, NPAIR, 0, stream>>>(hist, off);
        k_scatter<<<128, 256, 0, stream>>>(si, ti, hist, sorted);
        k_gemm<<<NPAIR, 512, 0, stream>>>(z, ew, dw, cp, dp, off, sorted, out);
    } else {
        k_fallback<<<1024, 256, 0, stream>>>(z, si, ti, ew, dw, cp, dp, out);
    }
}

// Round 4
// 145.361 us; speedup vs baseline: 2.6049x; 1.0107x over previous
//
#include <hip/hip_runtime.h>
#include <hip/hip_bf16.h>

// Problem constants (fixed by reference). ALL float tensors are float32;
// indices int32. MFMA runs on bf16-converted fragments; accumulate + epilogue
// in fp32.
#define NB     131072   // batch
#define NCH    16       // charts
#define NPAIR  256      // (src,tgt) pair buckets
#define LDW    136      // LDS weight-row stride in bf16 elems (16B-aligned rows)
#define LDH    136      // LDS h-row stride in bf16 elems
#define LDO    132      // (fallback path only)
#define CAP    1024     // sorted-slice chunk capacity (bucket avg 512, max ~640)

// Workspace layout (ints): hist/cursor @0 (256) | off @256 (257) | sorted @528 (NB)
#define WS_HIST   0
#define WS_OFF    256
#define WS_SORTED 528
#define WS_BYTES  ((WS_SORTED + NB) * 4)   // 526,400

typedef short short8 __attribute__((ext_vector_type(8)));   // 8 x bf16 (4 VGPRs) MFMA frag
typedef float f32x4  __attribute__((ext_vector_type(4)));   // MFMA accumulator / fp32 vec

__device__ __forceinline__ short bfbits(float x) {
    union { __hip_bfloat16 h; short s; } u;
    u.h = __float2bfloat16(x);
    return u.s;
}

// Load 8 consecutive fp32 (32B, 16B-aligned) and convert to a bf16x8 MFMA frag.
__device__ __forceinline__ short8 cvt_frag(const float* __restrict__ p) {
    const f32x4 lo = *(const f32x4*)p;
    const f32x4 hi = *(const f32x4*)(p + 4);
    short8 r;
    r[0] = bfbits(lo[0]); r[1] = bfbits(lo[1]); r[2] = bfbits(lo[2]); r[3] = bfbits(lo[3]);
    r[4] = bfbits(hi[0]); r[5] = bfbits(hi[1]); r[6] = bfbits(hi[2]); r[7] = bfbits(hi[3]);
    return r;
}

// Pack two f32x4 into one bf16x8 MFMA frag.
__device__ __forceinline__ short8 pack_frag(f32x4 lo, f32x4 hi) {
    short8 r;
    r[0] = bfbits(lo[0]); r[1] = bfbits(lo[1]); r[2] = bfbits(lo[2]); r[3] = bfbits(lo[3]);
    r[4] = bfbits(hi[0]); r[5] = bfbits(hi[1]); r[6] = bfbits(hi[2]); r[7] = bfbits(hi[3]);
    return r;
}

// ---------------------------------------------------------------- k_init ----
__global__ void k_init(int* __restrict__ hist) {
    hist[threadIdx.x] = 0;
}

// ---------------------------------------------------------------- k_hist ----
__global__ __launch_bounds__(256) void k_hist(const int* __restrict__ si,
                                              const int* __restrict__ ti,
                                              int* __restrict__ hist) {
    __shared__ int sh[NPAIR];
    const int t = threadIdx.x;
    sh[t] = 0;
    __syncthreads();
    const int base = blockIdx.x * 1024 + t;
#pragma unroll
    for (int j = 0; j < 4; ++j) {
        const int i = base + j * 256;                       // coalesced
        const int k = (si[i] * NCH + ti[i]) & (NPAIR - 1);  // masked: never OOB
        atomicAdd(&sh[k], 1);
    }
    __syncthreads();
    if (sh[t]) atomicAdd(&hist[t], sh[t]);
}

// ---------------------------------------------------------------- k_scan ----
__global__ __launch_bounds__(256) void k_scan(int* __restrict__ hist,
                                              int* __restrict__ off) {
    __shared__ int s[NPAIR];
    const int t = threadIdx.x;
    const int v = hist[t];
    s[t] = v;
    __syncthreads();
#pragma unroll
    for (int d = 1; d < NPAIR; d <<= 1) {
        const int x = (t >= d) ? s[t - d] : 0;
        __syncthreads();
        s[t] += x;
        __syncthreads();
    }
    off[t + 1] = s[t];                 // inclusive -> off[1..256]
    if (t == 0) off[0] = 0;
    hist[t] = s[t] - v;                // exclusive prefix -> cursor start
}

// ------------------------------------------------------------- k_scatter ----
__global__ __launch_bounds__(256) void k_scatter(const int* __restrict__ si,
                                                 const int* __restrict__ ti,
                                                 int* __restrict__ cursor,
                                                 int* __restrict__ sorted) {
    __shared__ int sh[NPAIR];
    __shared__ int sbase[NPAIR];
    const int t = threadIdx.x;
    sh[t] = 0;
    __syncthreads();
    int key[4], rank[4];
    const int base = blockIdx.x * 1024 + t;
#pragma unroll
    for (int j = 0; j < 4; ++j) {
        const int i = base + j * 256;
        const int k = (si[i] * NCH + ti[i]) & (NPAIR - 1);
        key[j]  = k;
        rank[j] = atomicAdd(&sh[k], 1);
    }
    __syncthreads();
    sbase[t] = sh[t] ? atomicAdd(&cursor[t], sh[t]) : 0;
    __syncthreads();
#pragma unroll
    for (int j = 0; j < 4; ++j) {
        const int slot = sbase[key[j]] + rank[j];
        if (slot >= 0 && slot < NB)
            sorted[slot] = base + j * 256;
    }
}

// ---------------------------------------------------------------- k_gemm ----
// ONE BLOCK PER BUCKET, 512 threads = 8 waves, wave-autonomous main loop
// (round-3 structure, zero main-loop barriers). Round-4 change: 32-ROW
// GROUPS. Round-3's 16-row groups re-read the full B panels from LDS per
// group: ~136 ds_read_b128 per 16 rows -> ~26K LDS-read cycles per CU, the
// dominant term. Two 16-row halves now SHARE every B fragment read (per
// k-step: 8 B reads feed 16 MFMAs), halving LDS-read traffic per row and
// halving loop iterations. Register plan (all statically indexed):
// stage bufs 64 + A-frags 32 + acc 64 ~= 190 VGPR < 256 budget, no spill.
__global__ __launch_bounds__(512, 2)
void k_gemm(const float* __restrict__ z,
            const float* __restrict__ encw,
            const float* __restrict__ decw,
            const float* __restrict__ cpar,
            const float* __restrict__ dpar,
            const int* __restrict__ off,
            const int* __restrict__ sorted,
            float* __restrict__ out) {
    __shared__ int sRowLds[CAP];                              //   4,096 B
    __shared__ __align__(16) __hip_bfloat16 sW1[128 * LDW];   //  34,816 B
    __shared__ __align__(16) __hip_bfloat16 sW2[128 * LDW];   //  34,816 B
    __shared__ __align__(16) __hip_bfloat16 sH[8 * 32 * LDH]; //  69,632 B (per-wave 32-row slices)

    const int bucket = blockIdx.x;
    const int srcc = bucket >> 4;
    const int tgtc = bucket & (NCH - 1);
    const int beg = off[bucket];
    const int end = off[bucket + 1];

    const int tid  = threadIdx.x;
    const int lane = tid & 63;
    const int wv   = tid >> 6;                  // 0..7
    const int lr   = lane & 15;                 // A: m-within-half / B: n-within-tile
    const int lhi  = lane >> 4;                 // k-chunk selector (8 elems each)

    // ---- stage W1/W2 (fp32 global, coalesced) -> bf16 LDS, once per block ----
    {
        const float* W1 = encw + srcc * 16384;  // [R=128][D=128] row-major fp32
        const float* W2 = decw + tgtc * 16384;  // [D=128][R=128] row-major fp32
#pragma unroll
        for (int it = 0; it < 4; ++it) {
            const int f = (it * 512 + tid) * 8;          // flat float index, 8 at a time
            const int row = f >> 7, col = f & 127;
            *(short8*)(sW1 + row * LDW + col) = cvt_frag(W1 + f);
            *(short8*)(sW2 + row * LDW + col) = cvt_frag(W2 + f);
        }
    }

    float cb[8], db[8];
#pragma unroll
    for (int nt = 0; nt < 8; ++nt) {
        cb[nt] = cpar[srcc * 128 + nt * 16 + lr];
        db[nt] = dpar[tgtc * 128 + nt * 16 + lr];
    }

    __hip_bfloat16* const hs = sH + wv * (32 * LDH);   // this wave's 32-row h slice

    // stage buffers for one 32-row group's A-operands (fp32, awaiting cvt)
    f32x4 bufA[8], bufB[8];   // half0 row (lr), half1 row (16+lr): 32 floats each

    // issue the 16 z-loads for group g (fire-and-forget; consumed by pack later)
    auto pf = [&](int g) {
        const int r0 = sRowLds[(g << 5) + lr];
        const int r1 = sRowLds[(g << 5) + 16 + lr];
        const float* p0 = z + (long)(r0 < 0 ? 0 : r0) * 128 + lhi * 8;
        const float* p1 = z + (long)(r1 < 0 ? 0 : r1) * 128 + lhi * 8;
#pragma unroll
        for (int k = 0; k < 4; ++k) {
            bufA[2 * k]     = *(const f32x4*)(p0 + k * 32);
            bufA[2 * k + 1] = *(const f32x4*)(p0 + k * 32 + 4);
            bufB[2 * k]     = *(const f32x4*)(p1 + k * 32);
            bufB[2 * k + 1] = *(const f32x4*)(p1 + k * 32 + 4);
        }
    };

    // chunked over the bucket (one chunk in practice: buckets avg 512, CAP 1024)
    for (int cb0 = beg; cb0 < end; cb0 += CAP) {
        const int cnt = min(end - cb0, CAP);
        __syncthreads();                       // protect sRowLds reuse across chunks
        for (int i = tid; i < CAP; i += 512) {
            int v = (i < cnt) ? sorted[cb0 + i] : -1;
            sRowLds[i] = ((unsigned)v < (unsigned)NB) ? v : -1;   // clamp: poison -> pad
        }
        __syncthreads();                       // weights (first chunk) + rows visible

        const int ng = (cnt + 31) >> 5;        // 32-row groups in this chunk
        int g = wv;
        if (g < ng) pf(g);
        while (g < ng) {
            // ---- pack stage buffers -> bf16 A-frags (waits on the loads),
            //      then immediately refill the freed buffers for the next group
            short8 a0[4], a1[4];
#pragma unroll
            for (int k = 0; k < 4; ++k) {
                a0[k] = pack_frag(bufA[2 * k], bufA[2 * k + 1]);
                a1[k] = pack_frag(bufB[2 * k], bufB[2 * k + 1]);
            }
            const int gn = g + 8;
            if (gn < ng) pf(gn);               // in flight during GEMM1+GEMM2

            // -------- GEMM1: both halves share each B fragment read --------
            f32x4 acc0[8], acc1[8];
#pragma unroll
            for (int nt = 0; nt < 8; ++nt) { acc0[nt] = (f32x4)(0.0f); acc1[nt] = (f32x4)(0.0f); }

#pragma unroll
            for (int k = 0; k < 4; ++k) {
#pragma unroll
                for (int nt = 0; nt < 8; ++nt) {
                    const short8 b = *(const short8*)(sW1 + (nt * 16 + lr) * LDW + k * 32 + lhi * 8);
                    acc0[nt] = __builtin_amdgcn_mfma_f32_16x16x32_bf16(a0[k], b, acc0[nt], 0, 0, 0);
                    acc1[nt] = __builtin_amdgcn_mfma_f32_16x16x32_bf16(a1[k], b, acc1[nt], 0, 0, 0);
                }
            }

            // h (+ c bias) -> per-wave LDS slice; C layout: row=lhi*4+r, col=nt*16+lr
            // same-wave DS ops are in-order; no barrier needed.
#pragma unroll
            for (int nt = 0; nt < 8; ++nt)
#pragma unroll
                for (int r = 0; r < 4; ++r) {
                    hs[(lhi * 4 + r) * LDH + nt * 16 + lr]        = __float2bfloat16(acc0[nt][r] + cb[nt]);
                    hs[(16 + lhi * 4 + r) * LDH + nt * 16 + lr]   = __float2bfloat16(acc1[nt][r] + cb[nt]);
                }

            // -------- GEMM2: A = h (per-wave slice), B = sW2, shared reads --------
#pragma unroll
            for (int nt = 0; nt < 8; ++nt) { acc0[nt] = (f32x4)(0.0f); acc1[nt] = (f32x4)(0.0f); }

#pragma unroll
            for (int k = 0; k < 4; ++k) {
                const short8 ah0 = *(const short8*)(hs + lr * LDH + k * 32 + lhi * 8);
                const short8 ah1 = *(const short8*)(hs + (16 + lr) * LDH + k * 32 + lhi * 8);
#pragma unroll
                for (int nt = 0; nt < 8; ++nt) {
                    const short8 b = *(const short8*)(sW2 + (nt * 16 + lr) * LDW + k * 32 + lhi * 8);
                    acc0[nt] = __builtin_amdgcn_mfma_f32_16x16x32_bf16(ah0, b, acc0[nt], 0, 0, 0);
                    acc1[nt] = __builtin_amdgcn_mfma_f32_16x16x32_bf16(ah1, b, acc1[nt], 0, 0, 0);
                }
            }

            // direct stores (+ d bias): per (nt,r) 16 lanes write 64B contiguous
            {
                int g0[4], g1[4];
#pragma unroll
                for (int r = 0; r < 4; ++r) {
                    g0[r] = sRowLds[(g << 5) + lhi * 4 + r];
                    g1[r] = sRowLds[(g << 5) + 16 + lhi * 4 + r];
                }
#pragma unroll
                for (int nt = 0; nt < 8; ++nt)
#pragma unroll
                    for (int r = 0; r < 4; ++r) {
                        if (g0[r] >= 0)
                            out[(long)g0[r] * 128 + nt * 16 + lr] = acc0[nt][r] + db[nt];
                        if (g1[r] >= 0)
                            out[(long)g1[r] * 128 + nt * 16 + lr] = acc1[nt][r] + db[nt];
                    }
            }
            g = gn;
        }
    }
}

// ------------------------------------------------------------- k_fallback ---
// Zero-workspace correct path: one wave per row, fp32 VALU dot products.
__global__ __launch_bounds__(256)
void k_fallback(const float* __restrict__ z,
                const int* __restrict__ si, const int* __restrict__ ti,
                const float* __restrict__ ew,
                const float* __restrict__ dw,
                const float* __restrict__ cp,
                const float* __restrict__ dp,
                float* __restrict__ out) {
    __shared__ float sh[4][128];
    const int lane = threadIdx.x & 63, wv = threadIdx.x >> 6;
    for (int row = blockIdx.x * 4 + wv; row < NB; row += (int)gridDim.x * 4) {
        const int sc = si[row] & (NCH - 1), tc = ti[row] & (NCH - 1);
        const float* zr = z + (long)row * 128;
        const float* W1 = ew + sc * 16384;
        float h0 = cp[sc * 128 + lane];
        float h1 = cp[sc * 128 + lane + 64];
        for (int d = 0; d < 128; ++d) {
            const float zv = zr[d];
            h0 += zv * W1[lane * 128 + d];
            h1 += zv * W1[(lane + 64) * 128 + d];
        }
        sh[wv][lane] = h0;
        sh[wv][lane + 64] = h1;
        __syncthreads();
        const float* W2 = dw + tc * 16384;
        float o0 = dp[tc * 128 + lane];
        float o1 = dp[tc * 128 + lane + 64];
        for (int r = 0; r < 128; ++r) {
            const float hv = sh[wv][r];
            o0 += hv * W2[lane * 128 + r];
            o1 += hv * W2[(lane + 64) * 128 + r];
        }
        out[(long)row * 128 + lane] = o0;
        out[(long)row * 128 + lane + 64] = o1;
        __syncthreads();
    }
}

// ----------------------------------------------------------------- launch ---
extern "C" void kernel_launch(void* const* d_in, const int* in_sizes, int n_in,
                              void* d_out, int out_size, void* d_ws, size_t ws_size,
                              hipStream_t stream) {
    // Reference dtypes: all float tensors float32, indices int32, output float32.
    const float* z  = (const float*)d_in[0];
    const int*   si = (const int*)d_in[1];
    const int*   ti = (const int*)d_in[2];
    const float* ew = (const float*)d_in[3];
    const float* dw = (const float*)d_in[4];
    const float* cp = (const float*)d_in[5];
    const float* dp = (const float*)d_in[6];
    float* out = (float*)d_out;

    if (ws_size >= (size_t)WS_BYTES) {
        int* hist   = (int*)d_ws + WS_HIST;    // 256, becomes cursor after scan
        int* off    = (int*)d_ws + WS_OFF;     // 257
        int* sorted = (int*)d_ws + WS_SORTED;  // NB

        k_init<<<1, NPAIR, 0, stream>>>(hist);
        k_hist<<<128, 256, 0, stream>>>(si, ti, hist);
        k_scan<<<1, NPAIR, 0, stream>>>(hist, off);
        k_scatter<<<128, 256, 0, stream>>>(si, ti, hist, sorted);
        k_gemm<<<NPAIR, 512, 0, stream>>>(z, ew, dw, cp, dp, off, sorted, out);
    } else {
        k_fallback<<<1024, 256, 0, stream>>>(z, si, ti, ew, dw, cp, dp, out);
    }
}